// Round 5
// baseline (444.834 us; speedup 1.0000x reference)
//
#include <hip/hip_runtime.h>

// BitNetAttention on MI355X (gfx950).
// Bitlinear matmuls are integer-exact in bf16 MFMA (activations = n*(max/127),
// weights = sign*scale; integer sums < 2^24 accumulate exactly in fp32).
// R1: XOR-swizzled LDS (conflicts 4.9e7 -> 0), fused QKV GEMM.
// R2/R3: S^T = K*Q^T formulation -> in-lane softmax.
// R4: attn q-tile 64 / k-tile 32 -> 37 KB LDS -> 4 blocks/CU (grid 1024 = 4/CU)
//     to break barrier phase-lock (was Occ 20%, Mfma 20.5 + VALU 31.8 both idle);
//     Ps padded stride-40 (no swizzle, no 4-way write conflicts);
//     vtrans fused into qkv V-epilogue (writes bf16 V^T directly).

#define DI __device__ __forceinline__

using bf16   = __bf16;
using bf16x4 = __attribute__((ext_vector_type(4))) __bf16;
using bf16x8 = __attribute__((ext_vector_type(8))) __bf16;
using f32x4  = __attribute__((ext_vector_type(4))) float;

DI void gl_lds16(void* lds, const void* g) {
  __builtin_amdgcn_global_load_lds((const __attribute__((address_space(1))) void*)g,
                                   (__attribute__((address_space(3))) void*)lds, 16, 0, 0);
}
DI float clampf(float x, float lo, float hi) { return fminf(fmaxf(x, lo), hi); }

DI float block_sum(float v, float* red, int lane, int w) {
#pragma unroll
  for (int o = 32; o > 0; o >>= 1) v += __shfl_xor(v, o, 64);
  __syncthreads();
  if (lane == 0) red[w] = v;
  __syncthreads();
  return red[0] + red[1] + red[2] + red[3];
}
DI float block_max(float v, float* red, int lane, int w) {
#pragma unroll
  for (int o = 32; o > 0; o >>= 1) v = fmaxf(v, __shfl_xor(v, o, 64));
  __syncthreads();
  if (lane == 0) red[w] = v;
  __syncthreads();
  return fmaxf(fmaxf(red[0], red[1]), fmaxf(red[2], red[3]));
}

// ---------------- weight stats ----------------
__global__ void wstats_kernel(const float* wq, const float* wk, const float* wv,
                              const float* wo, float* stats) {
  __shared__ float red[4], red2[4];
  int t = threadIdx.x, lane = t & 63, w = t >> 6;
  int m = blockIdx.y;
  const float* src; int n4;
  if (m == 0)      { src = wq; n4 = 1048576; }
  else if (m == 1) { src = wk; n4 = 524288;  }
  else if (m == 2) { src = wv; n4 = 524288;  }
  else             { src = wo; n4 = 1048576; }
  float s = 0.f, sa = 0.f;
  for (int i = blockIdx.x * 256 + t; i < n4; i += 256 * 256) {
    float4 v = ((const float4*)src)[i];
    s  += v.x + v.y + v.z + v.w;
    sa += fabsf(v.x) + fabsf(v.y) + fabsf(v.z) + fabsf(v.w);
  }
#pragma unroll
  for (int o = 32; o > 0; o >>= 1) { s += __shfl_xor(s, o, 64); sa += __shfl_xor(sa, o, 64); }
  if (lane == 0) { red[w] = s; red2[w] = sa; }
  __syncthreads();
  if (t == 0) {
    atomicAdd(&stats[2 * m],     red[0] + red[1] + red[2] + red[3]);
    atomicAdd(&stats[2 * m + 1], red2[0] + red2[1] + red2[2] + red2[3]);
  }
}

// ---------------- ternary sign quant ----------------
__global__ void wsign_kernel(const float* wq, const float* wk, const float* wv, const float* wo,
                             ushort* sq, ushort* sk, ushort* sv, ushort* so,
                             const float* stats) {
  int m = blockIdx.y;
  const float* src; ushort* dst; int n4; float cinv;
  if (m == 0)      { src = wq; dst = sq; n4 = 1048576; cinv = 1.f / 4194304.f; }
  else if (m == 1) { src = wk; dst = sk; n4 = 524288;  cinv = 1.f / 2097152.f; }
  else if (m == 2) { src = wv; dst = sv; n4 = 524288;  cinv = 1.f / 2097152.f; }
  else             { src = wo; dst = so; n4 = 1048576; cinv = 1.f / 4194304.f; }
  float e = stats[2 * m] * cinv;
  for (int i = blockIdx.x * 256 + threadIdx.x; i < n4; i += 1024 * 256) {
    float4 v = ((const float4*)src)[i];
    ushort4 o;
    o.x = v.x > e ? 0x3F80 : (v.x < e ? 0xBF80 : 0);
    o.y = v.y > e ? 0x3F80 : (v.y < e ? 0xBF80 : 0);
    o.z = v.z > e ? 0x3F80 : (v.z < e ? 0xBF80 : 0);
    o.w = v.w > e ? 0x3F80 : (v.w < e ? 0xBF80 : 0);
    ((ushort4*)dst)[i] = o;
  }
}

// ---------------- RoPE tables ----------------
__global__ void ropetab_kernel(float* ct, float* st) {
  int s = blockIdx.x, j = threadIdx.x;
  float invf = powf(10000.f, -(float)j * (1.f / 64.f));
  float a = (float)s * invf;
  ct[s * 64 + j] = cosf(a);
  st[s * 64 + j] = sinf(a);
}

// ---------------- fused RMSNorm + activation quant ----------------
DI void quant_one(const float* xs, const float* __restrict__ wt, bf16* __restrict__ a,
                  float* __restrict__ r, int row, int t, int lane, int w, float* red) {
  float4 w0 = ((const float4*)wt)[t * 2], w1 = ((const float4*)wt)[t * 2 + 1];
  float wv[8] = {w0.x, w0.y, w0.z, w0.w, w1.x, w1.y, w1.z, w1.w};
  float y[8]; float am = 0.f;
#pragma unroll
  for (int e = 0; e < 8; ++e) {
    y[e] = clampf(wv[e] * xs[e], -50.f, 50.f);
    am = fmaxf(am, fabsf(y[e]));
  }
  float mx = block_max(am, red, lane, w);
  float maxval = fmaxf(mx, 1e-4f);
  float sc = 127.f / maxval;
  bf16x8 q;
#pragma unroll
  for (int e = 0; e < 8; ++e) {
    float n = rintf(y[e] * sc);
    n = clampf(n, -128.f, 127.f);
    q[e] = (bf16)n;
  }
  *(bf16x8*)(a + (size_t)row * 2048 + t * 8) = q;
  if (t == 0) r[row] = maxval * (1.f / 127.f);
}

template <int NW>
__launch_bounds__(256)
__global__ void rqnorm_kernel(const float* __restrict__ x,
                              const float* __restrict__ w0, const float* __restrict__ w1,
                              const float* __restrict__ w2,
                              bf16* a0, bf16* a1, bf16* a2,
                              float* r0, float* r1, float* r2) {
  __shared__ float red[4];
  int t = threadIdx.x, lane = t & 63, w = t >> 6;
  int row = blockIdx.x;
  const float* xr = x + (size_t)row * 2048;
  float4 u0 = ((const float4*)xr)[t * 2], u1 = ((const float4*)xr)[t * 2 + 1];
  float xs[8] = {u0.x, u0.y, u0.z, u0.w, u1.x, u1.y, u1.z, u1.w};
  float ss = 0.f;
#pragma unroll
  for (int e = 0; e < 8; ++e) { xs[e] = clampf(xs[e], -100.f, 100.f); ss += xs[e] * xs[e]; }
  float tot = block_sum(ss, red, lane, w);
  float var = fmaxf(tot * (1.f / 2048.f), 1e-5f);
  float inv = 1.f / sqrtf(var + 1e-5f);
#pragma unroll
  for (int e = 0; e < 8; ++e) xs[e] = clampf(xs[e] * inv, -10.f, 10.f);
  quant_one(xs, w0, a0, r0, row, t, lane, w, red);
  if (NW > 1) quant_one(xs, w1, a1, r1, row, t, lane, w, red);
  if (NW > 2) quant_one(xs, w2, a2, r2, row, t, lane, w, red);
}

// ---------------- GEMM core: 128x128 tile, XOR-swizzled LDS ----------------
DI void mm_core(const bf16* __restrict__ Ag0, const bf16* __restrict__ Bg0,
                bf16* As, bf16* Bs, int w, int lane, f32x4 acc[2][8]) {
  int l15 = lane & 15, quad = lane >> 4;
  int srow = w * 8 + (lane >> 3);
  int sc_p = (lane & 7) * 8;
  int sc_g = ((lane & 7) ^ (lane >> 3)) * 8;
  const bf16* Ag = Ag0 + (size_t)srow * 2048 + sc_g;
  const bf16* Bg = Bg0 + (size_t)srow * 2048 + sc_g;
  bf16* Al = As + srow * 64 + sc_p;
  bf16* Bl = Bs + srow * 64 + sc_p;
  for (int kt = 0; kt < 32; ++kt) {
    size_t kb = (size_t)kt * 64;
#pragma unroll
    for (int i = 0; i < 4; ++i) {
      gl_lds16(Al + i * 32 * 64, Ag + (size_t)i * 32 * 2048 + kb);
      gl_lds16(Bl + i * 32 * 64, Bg + (size_t)i * 32 * 2048 + kb);
    }
    __syncthreads();
#pragma unroll
    for (int kc = 0; kc < 2; ++kc) {
      bf16x8 af[2], bfr[8];
#pragma unroll
      for (int mt = 0; mt < 2; ++mt)
        af[mt] = *(const bf16x8*)(As + (w * 32 + mt * 16 + l15) * 64 +
                                  (((kc * 4 + quad) ^ (l15 & 7)) * 8));
#pragma unroll
      for (int nt = 0; nt < 8; ++nt)
        bfr[nt] = *(const bf16x8*)(Bs + (nt * 16 + l15) * 64 +
                                   (((kc * 4 + quad) ^ (l15 & 7)) * 8));
#pragma unroll
      for (int mt = 0; mt < 2; ++mt)
#pragma unroll
        for (int nt = 0; nt < 8; ++nt)
          acc[mt][nt] = __builtin_amdgcn_mfma_f32_16x16x32_bf16(af[mt], bfr[nt], acc[mt][nt], 0, 0, 0);
    }
    __syncthreads();
  }
}

// ---------------- fused QKV projection GEMM (V writes V^T bf16 directly) ----------------
__launch_bounds__(256, 2)
__global__ void qkv_gemm(const bf16* __restrict__ Aq, const bf16* __restrict__ Ak,
                         const bf16* __restrict__ Av, const bf16* __restrict__ Ball,
                         const float* __restrict__ rq, const float* __restrict__ rk,
                         const float* __restrict__ rv, const float* __restrict__ stats,
                         bf16* __restrict__ qr, bf16* __restrict__ kr,
                         bf16* __restrict__ vt_out,
                         const float* __restrict__ ct, const float* __restrict__ st) {
  __shared__ bf16 As[128 * 64];
  __shared__ bf16 Bs[128 * 64];
  int t = threadIdx.x, w = t >> 6, lane = t & 63;
  int l15 = lane & 15, quad = lane >> 4;
  int x = blockIdx.x, m0 = blockIdx.y * 128;
  const bf16* A; const float* rs; float sw; int brow0;
  if (x < 16)      { A = Aq; rs = rq; sw = stats[1] * (1.f / 4194304.f); brow0 = x * 128; }
  else if (x < 24) { A = Ak; rs = rk; sw = stats[3] * (1.f / 2097152.f); brow0 = 2048 + (x - 16) * 128; }
  else             { A = Av; rs = rv; sw = stats[5] * (1.f / 2097152.f); brow0 = 3072 + (x - 24) * 128; }
  sw = fmaxf(sw, 1e-8f);
  f32x4 acc[2][8] = {};
  mm_core(A + (size_t)m0 * 2048, Ball + (size_t)brow0 * 2048, As, Bs, w, lane, acc);

  if (x < 24) {
    bf16* outb = (x < 16) ? qr : kr;
    int h = (x < 16) ? x : x - 16;
    int nh = (x < 16) ? 16 : 8;
#pragma unroll
    for (int mt = 0; mt < 2; ++mt)
#pragma unroll
      for (int r = 0; r < 4; ++r) {
        int row = m0 + w * 32 + mt * 16 + quad * 4 + r;
        float rsc = rs[row] * sw;
        int s = row & 2047, b = row >> 11;
        size_t base = ((size_t)(b * nh + h) * 2048 + s) * 128;
#pragma unroll
        for (int nt = 0; nt < 4; ++nt) {
          int d = nt * 16 + l15;
          float x1 = acc[mt][nt][r] * rsc;
          float x2 = acc[mt][nt + 4][r] * rsc;
          float c = ct[s * 64 + d], sn = st[s * 64 + d];
          outb[base + d]      = (bf16)(x1 * c - x2 * sn);
          outb[base + d + 64] = (bf16)(x2 * c + x1 * sn);
        }
      }
  } else {
    // V epilogue: write bf16 V^T [b, kvh, d, s] directly (4 consecutive s per reg)
    int n0x = (x - 24) * 128;
#pragma unroll
    for (int mt = 0; mt < 2; ++mt) {
      int token0 = m0 + w * 32 + mt * 16 + quad * 4;
      float rsc[4];
#pragma unroll
      for (int r = 0; r < 4; ++r) rsc[r] = rs[token0 + r] * sw;
      int bb = token0 >> 11, s0 = token0 & 2047;
#pragma unroll
      for (int nt = 0; nt < 8; ++nt) {
        int col = n0x + nt * 16 + l15;       // 0..1023
        int kvh2 = col >> 7, d = col & 127;
        bf16x4 pv;
#pragma unroll
        for (int r = 0; r < 4; ++r) pv[r] = (bf16)(acc[mt][nt][r] * rsc[r]);
        *(bf16x4*)(vt_out + ((size_t)(bb * 8 + kvh2) * 128 + d) * 2048 + s0) = pv;
      }
    }
  }
}

// ---------------- O projection GEMM ----------------
__launch_bounds__(256, 2)
__global__ void gemm_o(const bf16* __restrict__ A, const bf16* __restrict__ Bw,
                       const float* __restrict__ rs, const float* __restrict__ stats,
                       float* __restrict__ out) {
  __shared__ bf16 As[128 * 64];
  __shared__ bf16 Bs[128 * 64];
  int t = threadIdx.x, w = t >> 6, lane = t & 63;
  int l15 = lane & 15, quad = lane >> 4;
  int m0 = blockIdx.y * 128, n0 = blockIdx.x * 128;
  f32x4 acc[2][8] = {};
  mm_core(A + (size_t)m0 * 2048, Bw + (size_t)n0 * 2048, As, Bs, w, lane, acc);
  float sw = fmaxf(stats[7] * (1.f / 4194304.f), 1e-8f);
#pragma unroll
  for (int mt = 0; mt < 2; ++mt)
#pragma unroll
    for (int r = 0; r < 4; ++r) {
      int row = m0 + w * 32 + mt * 16 + quad * 4 + r;
      float rsc = rs[row] * sw;
#pragma unroll
      for (int nt = 0; nt < 8; ++nt)
        out[(size_t)row * 2048 + n0 + nt * 16 + l15] = acc[mt][nt][r] * rsc;
    }
}

// ---------------- flash attention: q-tile 64, k-tile 32, 4 blocks/CU ----------------
// S^T = K*Q^T (in-lane softmax); O^T = V^T*P. LDS 37 KB: Ks dbuf 2x8K (xor-16
// swizzle), Vs dbuf 2x8K (xor-4 swizzle), Ps 64x40 padded (conflict-free, no
// swizzle). Grid 1024 blocks = 4/CU = 16 waves/CU to overlap matrix/VALU phases.
__launch_bounds__(256, 4)
__global__ void attn_kernel(const bf16* __restrict__ Q, const bf16* __restrict__ Kc,
                            const bf16* __restrict__ Vt, const float* __restrict__ mask,
                            float* __restrict__ Oout) {
  constexpr float scale = 0.08838834764831845f; // 1/sqrt(128)
  __shared__ bf16 Ks[2][32 * 128];
  __shared__ bf16 Vs[2][128 * 32];
  __shared__ bf16 Ps[64 * 40];                  // stride 40 = 80B: conflict-free
  int t = threadIdx.x, w = t >> 6, lane = t & 63;
  int l15 = lane & 15, quad = lane >> 4;
  int bh = blockIdx.y, b = bh >> 4, h = bh & 15, kvh = h >> 1;
  int q0 = blockIdx.x * 64;
  const bf16* Qb = Q + (size_t)(b * 16 + h) * 2048 * 128;
  const bf16* Kb = Kc + (size_t)(b * 8 + kvh) * 2048 * 128;
  const bf16* Vb = Vt + (size_t)(b * 8 + kvh) * 128 * 2048;

  int qloc = w * 16 + l15;            // wave-private q row (16 per wave)
  int qg = q0 + qloc;

  bf16x8 qf[4];
#pragma unroll
  for (int kc = 0; kc < 4; ++kc)
    qf[kc] = *(const bf16x8*)(Qb + (size_t)qg * 128 + kc * 32 + quad * 8);

  f32x4 Oa[8] = {};
  float mrow = -1e30f, lrow = 0.f;

  // staging: Ks 32x128 (16 chunks/row, xor r&15); Vs 128x32 (4 chunks/row, xor r&3)
  int ksr = t >> 4;                    // 0..15
  int ksc_p = (t & 15) * 8;
  int ksc_g = ((t & 15) ^ ksr) * 8;
  int vsr = t >> 2;                    // 0..63
  int vsc_p = (t & 3) * 8;
  int vsc_g = ((t & 3) ^ (vsr & 3)) * 8;

  auto stage = [&](int buf, int kt) {
    int kk0 = kt * 32;
#pragma unroll
    for (int i = 0; i < 2; ++i)
      gl_lds16(&Ks[buf][(i * 16 + ksr) * 128 + ksc_p],
               Kb + (size_t)(kk0 + i * 16 + ksr) * 128 + ksc_g);
#pragma unroll
    for (int i = 0; i < 2; ++i)
      gl_lds16(&Vs[buf][(i * 64 + vsr) * 32 + vsc_p],
               Vb + (size_t)(i * 64 + vsr) * 2048 + kk0 + vsc_g);
  };

  stage(0, 0);

  f32x4 mv[2], mvn[2];
#pragma unroll
  for (int k2 = 0; k2 < 2; ++k2)
    mv[k2] = *(const f32x4*)(mask + (size_t)qg * 2048 + k2 * 16 + quad * 4);

  for (int kt = 0; kt < 64; ++kt) {
    int cur = kt & 1;
    __syncthreads();                  // drains prefetch issued one iter ago
    if (kt < 63) stage(cur ^ 1, kt + 1);

    // S^T = K Q^T
    f32x4 Sacc[2] = {};
#pragma unroll
    for (int kc = 0; kc < 4; ++kc) {
      bf16x8 kf[2];
#pragma unroll
      for (int k2 = 0; k2 < 2; ++k2)
        kf[k2] = *(const bf16x8*)(&Ks[cur][(k2 * 16 + l15) * 128 + (((kc * 4 + quad) ^ l15) * 8)]);
#pragma unroll
      for (int k2 = 0; k2 < 2; ++k2)
        Sacc[k2] = __builtin_amdgcn_mfma_f32_16x16x32_bf16(kf[k2], qf[kc], Sacc[k2], 0, 0, 0);
    }

    // prefetch next mask tile (off critical path)
    if (kt < 63) {
      int kk1 = (kt + 1) * 32;
#pragma unroll
      for (int k2 = 0; k2 < 2; ++k2)
        mvn[k2] = *(const f32x4*)(mask + (size_t)qg * 2048 + kk1 + k2 * 16 + quad * 4);
    }

    // online softmax (per lane: 8 k-values for q=qloc, in-lane tree + 2 shuffles)
#pragma unroll
    for (int k2 = 0; k2 < 2; ++k2)
#pragma unroll
      for (int r = 0; r < 4; ++r)
        Sacc[k2][r] = Sacc[k2][r] * scale + mv[k2][r];
    f32x4 vm;
#pragma unroll
    for (int r = 0; r < 4; ++r) vm[r] = fmaxf(Sacc[0][r], Sacc[1][r]);
    float mx = fmaxf(fmaxf(vm[0], vm[1]), fmaxf(vm[2], vm[3]));
    mx = fmaxf(mx, __shfl_xor(mx, 16, 64));
    mx = fmaxf(mx, __shfl_xor(mx, 32, 64));
    float mnew = fmaxf(mrow, mx);
    float alpha = __expf(mrow - mnew);
    mrow = mnew;
    f32x4 vs = {0.f, 0.f, 0.f, 0.f};
#pragma unroll
    for (int k2 = 0; k2 < 2; ++k2)
#pragma unroll
      for (int r = 0; r < 4; ++r) {
        float p = __expf(Sacc[k2][r] - mnew);
        Sacc[k2][r] = p;
        vs[r] += p;
      }
    float rsum = (vs[0] + vs[1]) + (vs[2] + vs[3]);
    rsum += __shfl_xor(rsum, 16, 64);
    rsum += __shfl_xor(rsum, 32, 64);
    lrow = lrow * alpha + rsum;
#pragma unroll
    for (int dt = 0; dt < 8; ++dt) Oa[dt] *= alpha;
    // P^T -> Ps[q][k], padded stride 40, wave-private rows
#pragma unroll
    for (int k2 = 0; k2 < 2; ++k2) {
      bf16x4 pk;
#pragma unroll
      for (int r = 0; r < 4; ++r) pk[r] = (bf16)Sacc[k2][r];
      *(bf16x4*)(&Ps[qloc * 40 + k2 * 16 + quad * 4]) = pk;
    }

    // O^T += V^T P (Ps rows wave-private: no barrier between write and read)
    bf16x8 pf = *(const bf16x8*)(&Ps[qloc * 40 + quad * 8]);
#pragma unroll
    for (int dt = 0; dt < 8; ++dt) {
      bf16x8 vf = *(const bf16x8*)(&Vs[cur][(dt * 16 + l15) * 32 + ((quad ^ (l15 & 3)) * 8)]);
      Oa[dt] = __builtin_amdgcn_mfma_f32_16x16x32_bf16(vf, pf, Oa[dt], 0, 0, 0);
    }

#pragma unroll
    for (int k2 = 0; k2 < 2; ++k2) mv[k2] = mvn[k2];
  }

  float inv = 1.f / lrow;
  int token = b * 2048 + qg;
#pragma unroll
  for (int dt = 0; dt < 8; ++dt) {
    f32x4 o = Oa[dt] * inv;
    *(f32x4*)(Oout + (size_t)token * 2048 + h * 128 + dt * 16 + quad * 4) = o;
  }
}

// ---------------- launch ----------------
extern "C" void kernel_launch(void* const* d_in, const int* in_sizes, int n_in,
                              void* d_out, int out_size, void* d_ws, size_t ws_size,
                              hipStream_t stream) {
  const float* hidden = (const float*)d_in[0];
  const float* mask   = (const float*)d_in[1];
  const float* wq = (const float*)d_in[2];
  const float* wk = (const float*)d_in[3];
  const float* wv = (const float*)d_in[4];
  const float* wo = (const float*)d_in[5];
  const float* nq = (const float*)d_in[6];
  const float* nk = (const float*)d_in[7];
  const float* nv = (const float*)d_in[8];
  const float* no = (const float*)d_in[9];
  float* out = (float*)d_out;
  char* ws = (char*)d_ws;

  constexpr size_t O_STATS = 0;
  constexpr size_t O_CT    = 256;
  constexpr size_t O_ST    = O_CT + 524288;
  constexpr size_t O_SQ    = O_ST + 524288;   // SQ|SK|SV|SO contiguous
  constexpr size_t O_SK    = O_SQ + 8388608;
  constexpr size_t O_SV    = O_SK + 4194304;
  constexpr size_t O_SO    = O_SV + 4194304;
  constexpr size_t O_RSQ   = O_SO + 8388608;
  constexpr size_t O_RSK   = O_RSQ + 16384;
  constexpr size_t O_RSV   = O_RSK + 16384;
  constexpr size_t O_RSO   = O_RSV + 16384;
  constexpr size_t O_AQQ   = O_RSO + 16384;
  constexpr size_t O_AQK   = O_AQQ + 16777216;
  constexpr size_t O_AQV   = O_AQK + 16777216;
  constexpr size_t O_QR    = O_AQV + 16777216;
  constexpr size_t O_KR    = O_QR + 16777216;
  constexpr size_t O_VT    = O_KR + 8388608;  // bf16 [2,8,128,2048] (written by qkv_gemm)
  constexpr size_t O_ATTN  = O_AQQ;           // alias: fp32 [4096,2048]
  constexpr size_t O_AQO   = O_AQV;           // alias

  float* stats = (float*)(ws + O_STATS);
  float* ct = (float*)(ws + O_CT);
  float* st = (float*)(ws + O_ST);

  (void)hipMemsetAsync(ws + O_STATS, 0, 256, stream);

  wstats_kernel<<<dim3(256, 4), 256, 0, stream>>>(wq, wk, wv, wo, stats);
  wsign_kernel<<<dim3(1024, 4), 256, 0, stream>>>(wq, wk, wv, wo,
      (ushort*)(ws + O_SQ), (ushort*)(ws + O_SK), (ushort*)(ws + O_SV), (ushort*)(ws + O_SO), stats);
  ropetab_kernel<<<dim3(2048), 64, 0, stream>>>(ct, st);

  rqnorm_kernel<3><<<dim3(4096), 256, 0, stream>>>(hidden, nq, nk, nv,
      (bf16*)(ws + O_AQQ), (bf16*)(ws + O_AQK), (bf16*)(ws + O_AQV),
      (float*)(ws + O_RSQ), (float*)(ws + O_RSK), (float*)(ws + O_RSV));

  qkv_gemm<<<dim3(32, 32), 256, 0, stream>>>(
      (const bf16*)(ws + O_AQQ), (const bf16*)(ws + O_AQK), (const bf16*)(ws + O_AQV),
      (const bf16*)(ws + O_SQ),
      (const float*)(ws + O_RSQ), (const float*)(ws + O_RSK), (const float*)(ws + O_RSV),
      stats, (bf16*)(ws + O_QR), (bf16*)(ws + O_KR), (bf16*)(ws + O_VT), ct, st);

  attn_kernel<<<dim3(32, 32), 256, 0, stream>>>(
      (const bf16*)(ws + O_QR), (const bf16*)(ws + O_KR), (const bf16*)(ws + O_VT),
      mask, (float*)(ws + O_ATTN));

  rqnorm_kernel<1><<<dim3(4096), 256, 0, stream>>>((const float*)(ws + O_ATTN), no, no, no,
      (bf16*)(ws + O_AQO), (bf16*)(ws + O_AQO), (bf16*)(ws + O_AQO),
      (float*)(ws + O_RSO), (float*)(ws + O_RSO), (float*)(ws + O_RSO));

  gemm_o<<<dim3(16, 32), 256, 0, stream>>>(
      (const bf16*)(ws + O_AQO), (const bf16*)(ws + O_SO), (float*)(ws + O_RSO), stats, out);

  (void)in_sizes; (void)n_in; (void)out_size; (void)ws_size;
}